// Round 12
// baseline (166150.793 us; speedup 1.0000x reference)
//
#include <hip/hip_runtime.h>
#include <stdint.h>

typedef float f32x4 __attribute__((ext_vector_type(4)));

#define SLEN 8192
#define NBLK 256
#define SLOT 192                       // 12 chunks x 16B per CU slot
#define RPAR (NBLK * SLOT)             // 49152 per parity
#define MB_OFF (2 * RPAR)              // ring = 2 parities
#define MB_STRIDE (2 * RPAR)           // per-XCD mailbox: 2 parities
#define WS_BYTES (MB_OFF + 8 * MB_STRIDE)   // 884736

// Slot layout (CU b, parity t&1, tag t):
//   chunks 0..7  : acc0 (no y-term) unit u, q: {a0,a1,a2,tag},{a3,0,0,tag} @ u*32+q*16
//   chunks 8..11 : layer-1 unit u: {h1, wffn*h1, 0, tag} @ 128+u*16
// Every CU stages ALL slots, reduces y locally, and redundantly computes
// gates0 + c0 (bitwise identical everywhere) -> full h0[t] local, 1 rendezvous.

static __device__ __forceinline__ void st_chunk(void* addr, f32x4 v) {
  asm volatile("global_store_dwordx4 %0, %1, off sc0 sc1"
               :: "v"(addr), "v"(v) : "memory");
}
static __device__ __forceinline__ void ld6_ic(const char* a, f32x4& v0, f32x4& v1,
                                              f32x4& v2, f32x4& v3, f32x4& v4, f32x4& v5) {
  asm volatile("global_load_dwordx4 %0, %6, off sc0 sc1\n\t"
               "global_load_dwordx4 %1, %6, off offset:16 sc0 sc1\n\t"
               "global_load_dwordx4 %2, %6, off offset:32 sc0 sc1\n\t"
               "global_load_dwordx4 %3, %6, off offset:48 sc0 sc1\n\t"
               "global_load_dwordx4 %4, %6, off offset:64 sc0 sc1\n\t"
               "global_load_dwordx4 %5, %6, off offset:80 sc0 sc1\n\t"
               "s_waitcnt vmcnt(0)"
               : "=&v"(v0), "=&v"(v1), "=&v"(v2), "=&v"(v3), "=&v"(v4), "=&v"(v5)
               : "v"(a) : "memory");
}
static __device__ __forceinline__ void ld6_mb(const char* a, f32x4& v0, f32x4& v1,
                                              f32x4& v2, f32x4& v3, f32x4& v4, f32x4& v5) {
  asm volatile("global_load_dwordx4 %0, %6, off sc0\n\t"
               "global_load_dwordx4 %1, %6, off offset:16 sc0\n\t"
               "global_load_dwordx4 %2, %6, off offset:32 sc0\n\t"
               "global_load_dwordx4 %3, %6, off offset:48 sc0\n\t"
               "global_load_dwordx4 %4, %6, off offset:64 sc0\n\t"
               "global_load_dwordx4 %5, %6, off offset:80 sc0\n\t"
               "s_waitcnt vmcnt(0)"
               : "=&v"(v0), "=&v"(v1), "=&v"(v2), "=&v"(v3), "=&v"(v4), "=&v"(v5)
               : "v"(a) : "memory");
}
static __device__ __forceinline__ void st6_mb(char* a, f32x4 v0, f32x4 v1, f32x4 v2,
                                              f32x4 v3, f32x4 v4, f32x4 v5) {
  asm volatile("global_store_dwordx4 %0, %1, off sc0\n\t"
               "global_store_dwordx4 %0, %2, off offset:16 sc0\n\t"
               "global_store_dwordx4 %0, %3, off offset:32 sc0\n\t"
               "global_store_dwordx4 %0, %4, off offset:48 sc0\n\t"
               "global_store_dwordx4 %0, %5, off offset:64 sc0\n\t"
               "global_store_dwordx4 %0, %6, off offset:80 sc0"
               :: "v"(a), "v"(v0), "v"(v1), "v"(v2), "v"(v3), "v"(v4), "v"(v5)
               : "memory");
}
static __device__ __forceinline__ bool t6(f32x4 v0, f32x4 v1, f32x4 v2, f32x4 v3,
                                          f32x4 v4, f32x4 v5, unsigned tg) {
  return __float_as_uint(v0.w) == tg && __float_as_uint(v1.w) == tg &&
         __float_as_uint(v2.w) == tg && __float_as_uint(v3.w) == tg &&
         __float_as_uint(v4.w) == tg && __float_as_uint(v5.w) == tg;
}

static __device__ __forceinline__ float sigm(float v) { return 1.f / (1.f + expf(-v)); }
static __device__ __forceinline__ float tanh_f(float v) {
  float e = expf(-2.f * fabsf(v));
  return copysignf((1.f - e) / (1.f + e), v);
}
static __device__ __forceinline__ float lstm_h(float a0, float a1, float a2, float a3,
                                               float& c) {
  float ii = sigm(a0), ff = sigm(a1), gg = tanh_f(a2), oo = sigm(a3);
  c = ff * c + ii * gg;
  return oo * tanh_f(c);
}
// wave64 sum via DPP; total lands in lane 63
static __device__ __forceinline__ float dpp_red(float x) {
  x += __int_as_float(__builtin_amdgcn_update_dpp(0, __float_as_int(x), 0x111, 0xf, 0xf, true));
  x += __int_as_float(__builtin_amdgcn_update_dpp(0, __float_as_int(x), 0x112, 0xf, 0xf, true));
  x += __int_as_float(__builtin_amdgcn_update_dpp(0, __float_as_int(x), 0x114, 0xf, 0xf, true));
  x += __int_as_float(__builtin_amdgcn_update_dpp(0, __float_as_int(x), 0x118, 0xf, 0xf, true));
  x += __int_as_float(__builtin_amdgcn_update_dpp(0, __float_as_int(x), 0x142, 0xa, 0xf, true));
  x += __int_as_float(__builtin_amdgcn_update_dpp(0, __float_as_int(x), 0x143, 0xc, 0xf, true));
  return x;
}
static __device__ __forceinline__ float dot4(f32x4 a, f32x4 b) {
  return a.x * b.x + a.y * b.y + a.z * b.z + a.w * b.w;
}
// padded layouts: chunk stride 20 floats (80B) -> conflict-free ds_read_b128
static __device__ __forceinline__ int lidx(int k)  { return (k >> 4) * 20 + (k & 15); }
static __device__ __forceinline__ int lidx4(int s) { return (s >> 2) * 20 + (s & 3) * 4; }

__global__ __launch_bounds__(512, 2) void lstm_fused(
    const float* __restrict__ x, const int* __restrict__ mask,
    const float* __restrict__ feat, const int* __restrict__ tfp,
    const float* __restrict__ w_ih0, const float* __restrict__ w_hh0,
    const float* __restrict__ b_ih0, const float* __restrict__ b_hh0,
    const float* __restrict__ w_ih1, const float* __restrict__ w_hh1,
    const float* __restrict__ b_ih1, const float* __restrict__ b_hh1,
    const float* __restrict__ w_ffn, const float* __restrict__ b_ffn,
    float* __restrict__ out, char* __restrict__ ws)
{
  char* ring = ws;
  const int tid = threadIdx.x, lane = tid & 63, wv = tid >> 6;
  const int blk = blockIdx.x;
  const int u = wv & 3;
  const int m = blk * 4 + u;            // owned hidden unit (both layers)
  const bool L1w = wv < 4;              // waves 0-3: layer-1 ; waves 4-7: layer-0
  const bool leader = blk < 8;          // one relay block per XCD (round-robin map)
  char* mbx = ws + MB_OFF + (blk & 7) * MB_STRIDE;
  const int s = tid >> 1, half = tid & 1;   // staging: slot s, 6 chunks per thread

  __shared__ __align__(16) float wh1_lds[16 * 1280];   // 80 KB
  __shared__ __align__(16) float lh0[1280];            // full h0 (local, redundant)
  __shared__ __align__(16) float lh1[2][1280];         // h1 parity-buffered
  __shared__ __align__(16) f32x4 aaccv[1024];          // staged acc0 per unit
  __shared__ float c0s[1024];                          // replicated layer-0 cell
  __shared__ float wBl[4][1024];                       // w_ih0[:,0] per gate
  __shared__ float lyp_cu[256];
  __shared__ float part[4];

  // ---- per-role weight matrix in VGPRs ----
  f32x4 W[4][4];
  {
    const float* Wsrc = L1w ? w_ih1 : w_hh0;
#pragma unroll
    for (int g = 0; g < 4; ++g) {
      const f32x4* sp = reinterpret_cast<const f32x4*>(
          Wsrc + (size_t)(1024 * g + m) * 1024 + lane * 16);
#pragma unroll
      for (int q = 0; q < 4; ++q) W[g][q] = sp[q];
    }
  }
  float wA[4];
#pragma unroll
  for (int g = 0; g < 4; ++g) {
    const int r = 1024 * g + m;
    if (L1w) {
      wA[g] = (lane == 16) ? (b_ih1[r] + b_hh1[r]) : 0.f;
    } else {
      wA[g] = (lane < 16) ? w_ih0[r * 16 + lane]
            : (lane == 16 ? (b_ih0[r] + b_hh0[r]) : 0.f);
    }
  }
  const float wffn_m = w_ffn[m];
  const float bf = b_ffn[0];
  float cc = 0.f;                       // c1 for L1 lane63
  int fdead = 0;

  // ---- stage w_hh1 into LDS (pad-20 layout) ----
  for (int ch = tid; ch < 1024; ch += 512) {
    const int r = ch >> 6, kc = ch & 63;
    const int grow = 1024 * (r & 3) + blk * 4 + (r >> 2);
    const f32x4* src = reinterpret_cast<const f32x4*>(
        w_hh1 + (size_t)grow * 1024 + kc * 16);
    f32x4* dst = reinterpret_cast<f32x4*>(&wh1_lds[r * 1280 + kc * 20]);
    dst[0] = src[0]; dst[1] = src[1]; dst[2] = src[2]; dst[3] = src[3];
  }
  // wB columns + replicated c0 init
  for (int i2 = tid; i2 < 4096; i2 += 512)
    wBl[i2 >> 10][i2 & 1023] = w_ih0[(size_t)((i2 >> 10) * 1024 + (i2 & 1023)) * 16];
  for (int i2 = tid; i2 < 1024; i2 += 512) c0s[i2] = 0.f;
  __syncthreads();

  const bool tf1 = (*tfp) >= 1;

  for (int t = 0; t < SLEN; ++t) {
    const bool use_x = (t == 0) || (tf1 && mask[t] != 0);
    const bool needy = (t > 0) && !use_x;
    const unsigned tg = (unsigned)t;
    char* rpar = ring + (t & 1) * RPAR;
    char* mpar = mbx + (t & 1) * RPAR;

    // ===== compute & direct lane-63 publish (no funnels, no pre-barrier) =====
    if (L1w) {
      if (t > 0) {
        __builtin_amdgcn_s_setprio(1);
        float a[4];
        const f32x4* h0v = reinterpret_cast<const f32x4*>(&lh0[lane * 20]);
        f32x4 p0 = h0v[0], p1 = h0v[1], p2 = h0v[2], p3 = h0v[3];
#pragma unroll
        for (int g = 0; g < 4; ++g)
          a[g] = wA[g] + dot4(W[g][0], p0) + dot4(W[g][1], p1) +
                          dot4(W[g][2], p2) + dot4(W[g][3], p3);
        if (t > 1) {
          const f32x4* h1v = reinterpret_cast<const f32x4*>(&lh1[t & 1][lane * 20]);
          f32x4 q0 = h1v[0], q1 = h1v[1], q2 = h1v[2], q3 = h1v[3];
#pragma unroll
          for (int g = 0; g < 4; ++g) {
            const f32x4* wb = reinterpret_cast<const f32x4*>(
                &wh1_lds[(u * 4 + g) * 1280 + lane * 20]);
            a[g] += dot4(wb[0], q0) + dot4(wb[1], q1) +
                    dot4(wb[2], q2) + dot4(wb[3], q3);
          }
        }
#pragma unroll
        for (int g = 0; g < 4; ++g) a[g] = dpp_red(a[g]);
        if (lane == 63) {
          float h = lstm_h(a[0], a[1], a[2], a[3], cc);
          f32x4 v; v.x = h; v.y = wffn_m * h; v.z = 0.f; v.w = __uint_as_float(tg);
          st_chunk(rpar + blk * SLOT + 128 + u * 16, v);
        }
        __builtin_amdgcn_s_setprio(0);
      } else if (lane == 63) {
        f32x4 v; v.x = 0.f; v.y = 0.f; v.z = 0.f; v.w = __uint_as_float(tg);
        st_chunk(rpar + blk * SLOT + 128 + u * 16, v);
      }
    } else {
      float base = (lane == 0) ? (use_x ? x[t] : 0.f)
                 : (lane < 16) ? feat[t * 15 + lane - 1]
                 : (lane == 16) ? 1.f : 0.f;
      float a[4];
#pragma unroll
      for (int g = 0; g < 4; ++g) a[g] = wA[g] * base;
      if (t > 0) {
        const f32x4* h0v = reinterpret_cast<const f32x4*>(&lh0[lane * 20]);
        f32x4 p0 = h0v[0], p1 = h0v[1], p2 = h0v[2], p3 = h0v[3];
#pragma unroll
        for (int g = 0; g < 4; ++g)
          a[g] += dot4(W[g][0], p0) + dot4(W[g][1], p1) +
                  dot4(W[g][2], p2) + dot4(W[g][3], p3);
      }
#pragma unroll
      for (int g = 0; g < 4; ++g) a[g] = dpp_red(a[g]);
      if (lane == 63) {
        f32x4 v0; v0.x = a[0]; v0.y = a[1]; v0.z = a[2]; v0.w = __uint_as_float(tg);
        f32x4 v1; v1.x = a[3]; v1.y = 0.f; v1.z = 0.f; v1.w = __uint_as_float(tg);
        st_chunk(rpar + blk * SLOT + u * 32, v0);
        st_chunk(rpar + blk * SLOT + u * 32 + 16, v1);
      }
    }

    // ===== the ONE rendezvous: stage 6 chunks of slot s =====
    {
      const char* icb = rpar + s * SLOT + half * 96;
      char* mbb = mpar + s * SLOT + half * 96;
      f32x4 v0, v1, v2, v3, v4, v5;
      if (leader) {
        ld6_ic(icb, v0, v1, v2, v3, v4, v5);
        while (!t6(v0, v1, v2, v3, v4, v5, tg)) ld6_ic(icb, v0, v1, v2, v3, v4, v5);
        st6_mb(mbb, v0, v1, v2, v3, v4, v5);
      } else {
        bool ok = false;
        if (fdead < 4) {
          ld6_mb(mbb, v0, v1, v2, v3, v4, v5);
          int tries = 0;
          while (!(ok = t6(v0, v1, v2, v3, v4, v5, tg))) {
            if (++tries >= 64) break;
            ld6_mb(mbb, v0, v1, v2, v3, v4, v5);
          }
          if (ok) fdead = 0; else ++fdead;
        }
        if (!ok) {
          ld6_ic(icb, v0, v1, v2, v3, v4, v5);
          while (!t6(v0, v1, v2, v3, v4, v5, tg)) {
            __builtin_amdgcn_s_sleep(2);
            ld6_ic(icb, v0, v1, v2, v3, v4, v5);
          }
        }
      }
      if (half == 0) {                  // chunks 0..5: acc0 units 0,1,2
        aaccv[s * 4 + 0] = f32x4{v0.x, v0.y, v0.z, v1.x};
        aaccv[s * 4 + 1] = f32x4{v2.x, v2.y, v2.z, v3.x};
        aaccv[s * 4 + 2] = f32x4{v4.x, v4.y, v4.z, v5.x};
      } else {                          // chunks 6..11: acc0 unit3 + 4x L1
        aaccv[s * 4 + 3] = f32x4{v0.x, v0.y, v0.z, v1.x};
        *reinterpret_cast<f32x4*>(&lh1[(t & 1) ^ 1][lidx4(s)]) =
            f32x4{v2.x, v3.x, v4.x, v5.x};
        lyp_cu[s] = (v2.y + v3.y) + (v4.y + v5.y);
      }
    }
    __syncthreads();  // B

    // ===== local y reduce =====
    if (wv < 4) {
      float p = lyp_cu[wv * 64 + lane];
      p = dpp_red(p);
      if (lane == 63) part[wv] = p;
    }
    __syncthreads();  // D

    // ===== redundant gates0: every CU computes full h0[t] + c0 update =====
    {
      const float yv = ((part[0] + part[1]) + (part[2] + part[3])) + bf;
      if (t > 0 && blk == 0 && tid == 0) out[t - 1] = yv;
      const int u0 = tid * 2;
#pragma unroll
      for (int k = 0; k < 2; ++k) {
        const int uu = u0 + k;
        f32x4 a = aaccv[uu];
        if (needy) {
          a.x += yv * wBl[0][uu]; a.y += yv * wBl[1][uu];
          a.z += yv * wBl[2][uu]; a.w += yv * wBl[3][uu];
        }
        float c = c0s[uu];
        float ii = sigm(a.x), ff = sigm(a.y), gg = tanh_f(a.z), oo = sigm(a.w);
        c = ff * c + ii * gg;
        c0s[uu] = c;
        lh0[lidx(uu)] = oo * tanh_f(c);
      }
    }
    __syncthreads();  // E
  }

  // ===== tail: h1[SLEN-1] -> out[SLEN-1] =====
  if (L1w) {
    float a[4];
    const f32x4* h0v = reinterpret_cast<const f32x4*>(&lh0[lane * 20]);
    f32x4 p0 = h0v[0], p1 = h0v[1], p2 = h0v[2], p3 = h0v[3];
#pragma unroll
    for (int g = 0; g < 4; ++g)
      a[g] = wA[g] + dot4(W[g][0], p0) + dot4(W[g][1], p1) +
                      dot4(W[g][2], p2) + dot4(W[g][3], p3);
    {
      const f32x4* h1v = reinterpret_cast<const f32x4*>(&lh1[SLEN & 1][lane * 20]);
      f32x4 q0 = h1v[0], q1 = h1v[1], q2 = h1v[2], q3 = h1v[3];
#pragma unroll
      for (int g = 0; g < 4; ++g) {
        const f32x4* wb = reinterpret_cast<const f32x4*>(
            &wh1_lds[(u * 4 + g) * 1280 + lane * 20]);
        a[g] += dot4(wb[0], q0) + dot4(wb[1], q1) +
                dot4(wb[2], q2) + dot4(wb[3], q3);
      }
    }
#pragma unroll
    for (int g = 0; g < 4; ++g) a[g] = dpp_red(a[g]);
    if (lane == 63) {
      float h = lstm_h(a[0], a[1], a[2], a[3], cc);
      f32x4 v; v.x = h; v.y = wffn_m * h; v.z = 0.f;
      v.w = __uint_as_float((unsigned)SLEN);
      st_chunk(ring + ((SLEN & 1) * RPAR) + blk * SLOT + 128 + u * 16, v);
    }
  }
  asm volatile("s_waitcnt vmcnt(0)" ::: "memory");

  if (blk == 0) {
    if (tid < 256) {
      const char* a0 = ring + ((SLEN & 1) * RPAR) + tid * SLOT + 128;
      f32x4 v0, v1, v2, v3;
      const unsigned tg = (unsigned)SLEN;
      for (;;) {
        asm volatile("global_load_dwordx4 %0, %4, off sc0 sc1\n\t"
                     "global_load_dwordx4 %1, %4, off offset:16 sc0 sc1\n\t"
                     "global_load_dwordx4 %2, %4, off offset:32 sc0 sc1\n\t"
                     "global_load_dwordx4 %3, %4, off offset:48 sc0 sc1\n\t"
                     "s_waitcnt vmcnt(0)"
                     : "=&v"(v0), "=&v"(v1), "=&v"(v2), "=&v"(v3)
                     : "v"(a0) : "memory");
        if (__float_as_uint(v0.w) == tg && __float_as_uint(v1.w) == tg &&
            __float_as_uint(v2.w) == tg && __float_as_uint(v3.w) == tg) break;
        __builtin_amdgcn_s_sleep(2);
      }
      lyp_cu[tid] = (v0.y + v1.y) + (v2.y + v3.y);
    }
    __syncthreads();
    if (wv < 4) {
      float p = lyp_cu[wv * 64 + lane];
      p = dpp_red(p);
      if (lane == 63) part[wv] = p;
    }
    __syncthreads();
    if (tid == 0) out[SLEN - 1] = ((part[0] + part[1]) + (part[2] + part[3])) + bf;
  }
}

extern "C" void kernel_launch(void* const* d_in, const int* in_sizes, int n_in,
                              void* d_out, int out_size, void* d_ws, size_t ws_size,
                              hipStream_t stream) {
  (void)in_sizes; (void)n_in; (void)out_size; (void)ws_size;
  const float* x      = (const float*)d_in[0];
  const int*   mask   = (const int*)  d_in[1];
  const float* feat   = (const float*)d_in[2];
  const int*   tfp    = (const int*)  d_in[3];
  const float* w_ih0  = (const float*)d_in[4];
  const float* w_hh0  = (const float*)d_in[5];
  const float* b_ih0  = (const float*)d_in[6];
  const float* b_hh0  = (const float*)d_in[7];
  const float* w_ih1  = (const float*)d_in[8];
  const float* w_hh1  = (const float*)d_in[9];
  const float* b_ih1  = (const float*)d_in[10];
  const float* b_hh1  = (const float*)d_in[11];
  const float* w_ffn  = (const float*)d_in[12];
  const float* b_ffn  = (const float*)d_in[13];
  float* out = (float*)d_out;
  char*  ws  = (char*)d_ws;

  // invalidate all ring + mailbox tags (0xFFFFFFFF never equals a step index)
  hipMemsetAsync(d_ws, 0xFF, (size_t)WS_BYTES, stream);

  lstm_fused<<<dim3(NBLK), dim3(512), 0, stream>>>(
      x, mask, feat, tfp, w_ih0, w_hh0, b_ih0, b_hh0,
      w_ih1, w_hh1, b_ih1, b_hh1, w_ffn, b_ffn, out, ws);
}

// Round 13
// 48604.666 us; speedup vs baseline: 3.4184x; 3.4184x over previous
//
#include <hip/hip_runtime.h>
#include <stdint.h>

typedef float f32x4 __attribute__((ext_vector_type(4)));

#define SLEN 8192
#define NBLK 256

// h1 ring @0     : 2 par x 256 CU x 32B {h0,h1,h2,tag},{h3,ypsum,0,tag} (funneled)
// h0 ring @16384 : 2 par x 256 CU x 64B, 4 chunks {h_u,0,0,tag} (direct lane63)
// mailboxes @49152: per XCD 49152B = h1 2x8192 @0 + h0 2x16384 @16384
#define H0_RING 16384
#define MB_OFF  49152
#define MB_STRIDE 49152
#define MB_H0   16384
#define WS_BYTES (MB_OFF + 8 * MB_STRIDE)   // 442368

static __device__ __forceinline__ void st_chunk(void* addr, f32x4 v) {
  asm volatile("global_store_dwordx4 %0, %1, off sc0 sc1"
               :: "v"(addr), "v"(v) : "memory");
}
static __device__ __forceinline__ void ld32(const void* a, f32x4& v0, f32x4& v1) {
  asm volatile("global_load_dwordx4 %0, %2, off sc0 sc1\n\t"
               "global_load_dwordx4 %1, %2, off offset:16 sc0 sc1\n\t"
               "s_waitcnt vmcnt(0)"
               : "=v"(v0), "=v"(v1) : "v"(a) : "memory");
}
static __device__ __forceinline__ void poll32(const void* a, unsigned tag,
                                              f32x4& v0, f32x4& v1) {
  ld32(a, v0, v1);
  while (__float_as_uint(v0.w) != tag || __float_as_uint(v1.w) != tag) {
    __builtin_amdgcn_s_sleep(2);
    ld32(a, v0, v1);
  }
}
static __device__ __forceinline__ void poll32_ns(const void* a, unsigned tag,
                                                 f32x4& v0, f32x4& v1) {
  ld32(a, v0, v1);
  while (__float_as_uint(v0.w) != tag || __float_as_uint(v1.w) != tag) {
    ld32(a, v0, v1);
  }
}
static __device__ __forceinline__ void ld32_mb(const void* a, f32x4& v0, f32x4& v1) {
  asm volatile("global_load_dwordx4 %0, %2, off sc0\n\t"
               "global_load_dwordx4 %1, %2, off offset:16 sc0\n\t"
               "s_waitcnt vmcnt(0)"
               : "=v"(v0), "=v"(v1) : "v"(a) : "memory");
}
static __device__ __forceinline__ void st_mb(void* a, f32x4 v0, f32x4 v1) {
  asm volatile("global_store_dwordx4 %0, %1, off sc0\n\t"
               "global_store_dwordx4 %0, %2, off offset:16 sc0"
               :: "v"(a), "v"(v0), "v"(v1) : "memory");
}
static __device__ __forceinline__ void poll_rly(const void* mb, const void* ic,
                                                unsigned tag, f32x4& v0, f32x4& v1,
                                                int& dead) {
  if (dead < 4) {
    ld32_mb(mb, v0, v1);
    int tries = 0;
    while (__float_as_uint(v0.w) != tag || __float_as_uint(v1.w) != tag) {
      if (++tries >= 64) break;
      ld32_mb(mb, v0, v1);
    }
    if (__float_as_uint(v0.w) == tag && __float_as_uint(v1.w) == tag) {
      dead = 0;
      return;
    }
    ++dead;
  }
  poll32(ic, tag, v0, v1);
}

static __device__ __forceinline__ float sigm(float v) { return 1.f / (1.f + expf(-v)); }
static __device__ __forceinline__ float tanh_f(float v) {
  float e = expf(-2.f * fabsf(v));
  return copysignf((1.f - e) / (1.f + e), v);
}
static __device__ __forceinline__ float lstm_h(float a0, float a1, float a2, float a3,
                                               float& c) {
  float ii = sigm(a0), ff = sigm(a1), gg = tanh_f(a2), oo = sigm(a3);
  c = ff * c + ii * gg;
  return oo * tanh_f(c);
}
// wave64 sum via DPP; total lands in lane 63
static __device__ __forceinline__ float dpp_red(float x) {
  x += __int_as_float(__builtin_amdgcn_update_dpp(0, __float_as_int(x), 0x111, 0xf, 0xf, true));
  x += __int_as_float(__builtin_amdgcn_update_dpp(0, __float_as_int(x), 0x112, 0xf, 0xf, true));
  x += __int_as_float(__builtin_amdgcn_update_dpp(0, __float_as_int(x), 0x114, 0xf, 0xf, true));
  x += __int_as_float(__builtin_amdgcn_update_dpp(0, __float_as_int(x), 0x118, 0xf, 0xf, true));
  x += __int_as_float(__builtin_amdgcn_update_dpp(0, __float_as_int(x), 0x142, 0xa, 0xf, true));
  x += __int_as_float(__builtin_amdgcn_update_dpp(0, __float_as_int(x), 0x143, 0xc, 0xf, true));
  return x;
}
static __device__ __forceinline__ float dot4(f32x4 a, f32x4 b) {
  return a.x * b.x + a.y * b.y + a.z * b.z + a.w * b.w;
}
// padded layout: chunk stride 20 floats (80B) -> conflict-free ds_read_b128
static __device__ __forceinline__ int lidx(int k)   { return (k >> 4) * 20 + (k & 15); }
static __device__ __forceinline__ int lidx4(int j)  { return (j >> 2) * 20 + (j & 3) * 4; }

__global__ __launch_bounds__(512, 2) void lstm_fused(
    const float* __restrict__ x, const int* __restrict__ mask,
    const float* __restrict__ feat, const int* __restrict__ tfp,
    const float* __restrict__ w_ih0, const float* __restrict__ w_hh0,
    const float* __restrict__ b_ih0, const float* __restrict__ b_hh0,
    const float* __restrict__ w_ih1, const float* __restrict__ w_hh1,
    const float* __restrict__ b_ih1, const float* __restrict__ b_hh1,
    const float* __restrict__ w_ffn, const float* __restrict__ b_ffn,
    float* __restrict__ out, char* __restrict__ ws)
{
  char* h1ring = ws;
  char* h0ring = ws + H0_RING;
  const int tid = threadIdx.x, lane = tid & 63, wv = tid >> 6;
  const int blk = blockIdx.x;
  const int u = wv & 3;
  const int m = blk * 4 + u;            // owned hidden unit (both layers)
  const bool L1w = wv < 4;              // waves 0-3: layer-1 ; waves 4-7: layer-0
  const bool leader = blk < 8;          // one relay block per XCD
  char* mbx = ws + MB_OFF + (blk & 7) * MB_STRIDE;

  __shared__ __align__(16) float wh1_lds[16 * 1280];   // 80 KB
  __shared__ __align__(16) float lh0[1280];
  __shared__ __align__(16) float lh1[1280];
  __shared__ float g1h[4], g1yp[4];
  __shared__ float ypv[2][4];
  __shared__ float lyp_t[256];
  __shared__ float part[4];

  // ---- per-role weight matrix in VGPRs ----
  f32x4 W[4][4];
  {
    const float* Wsrc = L1w ? w_ih1 : w_hh0;
#pragma unroll
    for (int g = 0; g < 4; ++g) {
      const f32x4* sp = reinterpret_cast<const f32x4*>(
          Wsrc + (size_t)(1024 * g + m) * 1024 + lane * 16);
#pragma unroll
      for (int q = 0; q < 4; ++q) W[g][q] = sp[q];
    }
  }
  float wA[4], wB[4];
#pragma unroll
  for (int g = 0; g < 4; ++g) {
    const int r = 1024 * g + m;
    if (L1w) {
      wA[g] = (lane == 16) ? (b_ih1[r] + b_hh1[r]) : 0.f;
      wB[g] = 0.f;
    } else {
      wA[g] = (lane < 16) ? w_ih0[r * 16 + lane]
            : (lane == 16 ? (b_ih0[r] + b_hh0[r]) : 0.f);
      wB[g] = w_ih0[r * 16];
    }
  }
  const float wffn_m = w_ffn[m];
  const f32x4 wffn4 = L1w ? reinterpret_cast<const f32x4*>(w_ffn)[tid & 255]
                          : f32x4{0.f, 0.f, 0.f, 0.f};
  const float bf = b_ffn[0];
  float cc = 0.f;
  int fb0 = 0, fb1 = 0;

  // ---- stage w_hh1 into LDS (pad-20 layout) ----
  for (int ch = tid; ch < 1024; ch += 512) {
    const int r = ch >> 6, kc = ch & 63;
    const int grow = 1024 * (r & 3) + blk * 4 + (r >> 2);
    const f32x4* src = reinterpret_cast<const f32x4*>(
        w_hh1 + (size_t)grow * 1024 + kc * 16);
    f32x4* dst = reinterpret_cast<f32x4*>(&wh1_lds[r * 1280 + kc * 20]);
    dst[0] = src[0]; dst[1] = src[1]; dst[2] = src[2]; dst[3] = src[3];
  }
  __syncthreads();

  const bool tf1 = (*tfp) >= 1;
  float acc0[4];

  // staging helpers
  auto stage_h0 = [&](int t) {
    const unsigned tg = (unsigned)t;
    const int j = tid >> 1, half = tid & 1;
    const char* ic = h0ring + (t & 1) * 16384 + j * 64 + half * 32;
    char* mb = mbx + MB_H0 + (t & 1) * 16384 + j * 64 + half * 32;
    f32x4 v0, v1;
    if (leader) { poll32_ns(ic, tg, v0, v1); st_mb(mb, v0, v1); }
    else        { poll_rly(mb, ic, tg, v0, v1, fb0); }
    const int b = lidx(j * 4 + half * 2);
    lh0[b] = v0.x; lh0[b + 1] = v1.x;
  };
  auto stage_h1 = [&](int t) {      // L1w threads only, t>0
    const unsigned tg = (unsigned)(t - 1);
    const char* ic = h1ring + ((t - 1) & 1) * 8192 + tid * 32;
    char* mb = mbx + ((t - 1) & 1) * 8192 + tid * 32;
    f32x4 v0, v1;
    if (leader) { poll32_ns(ic, tg, v0, v1); st_mb(mb, v0, v1); }
    else        { poll_rly(mb, ic, tg, v0, v1, fb1); }
    f32x4 h4; h4.x = v0.x; h4.y = v0.y; h4.z = v0.z; h4.w = v1.x;
    *reinterpret_cast<f32x4*>(&lh1[lidx4(tid)]) = h4;
    float p = dpp_red(dot4(wffn4, h4));
    if (lane == 63) ypv[(t - 1) & 1][u] = p;
  };

  for (int t = 0; t < SLEN; ++t) {
    const bool use_x = (t == 0) || (tf1 && mask[t] != 0);
    const bool needy = !use_x;
    const unsigned tg = (unsigned)t;

    // ===== P1: L1 computes h1[t-1]; L0 matvec (+use_x gates & direct publish) =====
    if (L1w) {
      if (t > 0) {
        __builtin_amdgcn_s_setprio(1);
        float a[4];
        const f32x4* h0v = reinterpret_cast<const f32x4*>(&lh0[lane * 20]);
        f32x4 p0 = h0v[0], p1 = h0v[1], p2 = h0v[2], p3 = h0v[3];
#pragma unroll
        for (int g = 0; g < 4; ++g)
          a[g] = wA[g] + dot4(W[g][0], p0) + dot4(W[g][1], p1) +
                          dot4(W[g][2], p2) + dot4(W[g][3], p3);
        if (t > 1) {
          const f32x4* h1v = reinterpret_cast<const f32x4*>(&lh1[lane * 20]);
          f32x4 q0 = h1v[0], q1 = h1v[1], q2 = h1v[2], q3 = h1v[3];
#pragma unroll
          for (int g = 0; g < 4; ++g) {
            const f32x4* wb = reinterpret_cast<const f32x4*>(
                &wh1_lds[(u * 4 + g) * 1280 + lane * 20]);
            a[g] += dot4(wb[0], q0) + dot4(wb[1], q1) +
                    dot4(wb[2], q2) + dot4(wb[3], q3);
          }
        }
#pragma unroll
        for (int g = 0; g < 4; ++g) a[g] = dpp_red(a[g]);
        if (lane == 63) {
          float h = lstm_h(a[0], a[1], a[2], a[3], cc);
          g1h[u] = h; g1yp[u] = wffn_m * h;
        }
        __builtin_amdgcn_s_setprio(0);
      }
    } else {
      // deferred out[t-2] (step t-1 used x)
      if (blk == 0 && wv == 7 && lane == 0 && t >= 2 && (tf1 && mask[t - 1] != 0)) {
        const int sl = t & 1;     // == (t-2)&1
        out[t - 2] = ((ypv[sl][0] + ypv[sl][1]) + (ypv[sl][2] + ypv[sl][3])) + bf;
      }
      float base = (lane == 0) ? (use_x ? x[t] : 0.f)
                 : (lane < 16) ? feat[t * 15 + lane - 1]
                 : (lane == 16) ? 1.f : 0.f;
#pragma unroll
      for (int g = 0; g < 4; ++g) acc0[g] = wA[g] * base;
      if (t > 0) {
        const f32x4* h0v = reinterpret_cast<const f32x4*>(&lh0[lane * 20]);
        f32x4 p0 = h0v[0], p1 = h0v[1], p2 = h0v[2], p3 = h0v[3];
#pragma unroll
        for (int g = 0; g < 4; ++g)
          acc0[g] += dot4(W[g][0], p0) + dot4(W[g][1], p1) +
                     dot4(W[g][2], p2) + dot4(W[g][3], p3);
      }
#pragma unroll
      for (int g = 0; g < 4; ++g) acc0[g] = dpp_red(acc0[g]);
      if (use_x && lane == 63) {   // gates + EARLY direct publish (pre-A!)
        float h = lstm_h(acc0[0], acc0[1], acc0[2], acc0[3], cc);
        f32x4 v; v.x = h; v.y = 0.f; v.z = 0.f; v.w = __uint_as_float(tg);
        st_chunk(h0ring + (t & 1) * 16384 + blk * 64 + u * 16, v);
      }
    }
    __syncthreads();  // A

    // funnel-publish h1[t-1]
    if (t > 0 && tid < 2) {
      f32x4 v;
      if (tid == 0) { v.x = g1h[0]; v.y = g1h[1]; v.z = g1h[2]; }
      else { v.x = g1h[3]; v.y = (g1yp[0] + g1yp[1]) + (g1yp[2] + g1yp[3]); v.z = 0.f; }
      v.w = __uint_as_float((unsigned)(t - 1));
      st_chunk(h1ring + ((t - 1) & 1) * 8192 + blk * 32 + tid * 16, v);
    }

    // ===== staging =====
    if (L1w) {
      if (!needy) {
        stage_h0(t);
        if (t > 0) stage_h1(t);
      } else {
        stage_h1(t);
      }
    }
    if (needy) {
      __syncthreads();  // B: ypv[(t-1)&1] complete
      if (!L1w && lane == 63) {
        __builtin_amdgcn_s_setprio(1);
        const int sl = (t - 1) & 1;
        float yy = ((ypv[sl][0] + ypv[sl][1]) + (ypv[sl][2] + ypv[sl][3])) + bf;
        if (blk == 0 && wv == 4) out[t - 1] = yy;
#pragma unroll
        for (int g = 0; g < 4; ++g) acc0[g] += yy * wB[g];
        float h = lstm_h(acc0[0], acc0[1], acc0[2], acc0[3], cc);
        f32x4 v; v.x = h; v.y = 0.f; v.z = 0.f; v.w = __uint_as_float(tg);
        st_chunk(h0ring + (t & 1) * 16384 + blk * 64 + u * 16, v);
        __builtin_amdgcn_s_setprio(0);
      }
      if (L1w) stage_h0(t);
    }
    if (!L1w) stage_h0(t);
    __syncthreads();  // E
  }

  // ===== tail: deferred out[SLEN-2], h1[SLEN-1], out[SLEN-1] =====
  if (blk == 0 && wv == 7 && lane == 0 && (tf1 && mask[SLEN - 1] != 0)) {
    const int sl = SLEN & 1;   // (SLEN-2)&1
    out[SLEN - 2] = ((ypv[sl][0] + ypv[sl][1]) + (ypv[sl][2] + ypv[sl][3])) + bf;
  }
  if (L1w) {
    float a[4];
    const f32x4* h0v = reinterpret_cast<const f32x4*>(&lh0[lane * 20]);
    f32x4 p0 = h0v[0], p1 = h0v[1], p2 = h0v[2], p3 = h0v[3];
#pragma unroll
    for (int g = 0; g < 4; ++g)
      a[g] = wA[g] + dot4(W[g][0], p0) + dot4(W[g][1], p1) +
                      dot4(W[g][2], p2) + dot4(W[g][3], p3);
    {
      const f32x4* h1v = reinterpret_cast<const f32x4*>(&lh1[lane * 20]);
      f32x4 q0 = h1v[0], q1 = h1v[1], q2 = h1v[2], q3 = h1v[3];
#pragma unroll
      for (int g = 0; g < 4; ++g) {
        const f32x4* wb = reinterpret_cast<const f32x4*>(
            &wh1_lds[(u * 4 + g) * 1280 + lane * 20]);
        a[g] += dot4(wb[0], q0) + dot4(wb[1], q1) +
                dot4(wb[2], q2) + dot4(wb[3], q3);
      }
    }
#pragma unroll
    for (int g = 0; g < 4; ++g) a[g] = dpp_red(a[g]);
    if (lane == 63) {
      float h = lstm_h(a[0], a[1], a[2], a[3], cc);
      g1h[u] = h; g1yp[u] = wffn_m * h;
    }
  }
  __syncthreads();
  if (tid < 2) {
    f32x4 v;
    if (tid == 0) { v.x = g1h[0]; v.y = g1h[1]; v.z = g1h[2]; }
    else { v.x = g1h[3]; v.y = (g1yp[0] + g1yp[1]) + (g1yp[2] + g1yp[3]); v.z = 0.f; }
    v.w = __uint_as_float((unsigned)(SLEN - 1));
    st_chunk(h1ring + ((SLEN - 1) & 1) * 8192 + blk * 32 + tid * 16, v);
  }
  if (blk == 0) {
    if (tid < 256) {
      f32x4 v0, v1;
      poll32(h1ring + ((SLEN - 1) & 1) * 8192 + tid * 32, (unsigned)(SLEN - 1), v0, v1);
      lyp_t[tid] = v1.y;
    }
    __syncthreads();
    if (wv < 4) {
      float p = dpp_red(lyp_t[wv * 64 + lane]);
      if (lane == 63) part[wv] = p;
    }
    __syncthreads();
    if (tid == 0) out[SLEN - 1] = ((part[0] + part[1]) + (part[2] + part[3])) + bf;
  }
}

extern "C" void kernel_launch(void* const* d_in, const int* in_sizes, int n_in,
                              void* d_out, int out_size, void* d_ws, size_t ws_size,
                              hipStream_t stream) {
  (void)in_sizes; (void)n_in; (void)out_size; (void)ws_size;
  const float* x      = (const float*)d_in[0];
  const int*   mask   = (const int*)  d_in[1];
  const float* feat   = (const float*)d_in[2];
  const int*   tfp    = (const int*)  d_in[3];
  const float* w_ih0  = (const float*)d_in[4];
  const float* w_hh0  = (const float*)d_in[5];
  const float* b_ih0  = (const float*)d_in[6];
  const float* b_hh0  = (const float*)d_in[7];
  const float* w_ih1  = (const float*)d_in[8];
  const float* w_hh1  = (const float*)d_in[9];
  const float* b_ih1  = (const float*)d_in[10];
  const float* b_hh1  = (const float*)d_in[11];
  const float* w_ffn  = (const float*)d_in[12];
  const float* b_ffn  = (const float*)d_in[13];
  float* out = (float*)d_out;
  char*  ws  = (char*)d_ws;

  // invalidate all ring + mailbox tags (0xFFFFFFFF never equals a step index)
  hipMemsetAsync(d_ws, 0xFF, (size_t)WS_BYTES, stream);

  lstm_fused<<<dim3(NBLK), dim3(512), 0, stream>>>(
      x, mask, feat, tfp, w_ih0, w_hh0, b_ih0, b_hh0,
      w_ih1, w_hh1, b_ih1, b_hh1, w_ffn, b_ffn, out, ws);
}

// Round 14
// 47601.532 us; speedup vs baseline: 3.4905x; 1.0211x over previous
//
#include <hip/hip_runtime.h>
#include <stdint.h>

typedef float f32x4 __attribute__((ext_vector_type(4)));

#define SLEN 8192
#define NBLK 256

// IC rings: h1 at byte 0, h0 at 16384. Each: 2 parities x 256 CUs x 2 chunks x 16B.
// CU b, chunk0 = {h[4b],h[4b+1],h[4b+2],tag}, chunk1 = {h[4b+3], ypsum_b, 0, tag}
// Ring traffic: sc0 sc1 (IC-coherent). Leaders (blk<8) relay ring -> per-XCD
// mailbox with sc0-only ops (XCD-local L2); followers poll the mailbox.
#define RING_PAR 8192
#define H0_OFF   16384
#define MB_OFF   32768
#define MB_STRIDE 32768            // per XCD: 2 par x (h1 8KB @0 + h0 8KB @8192)
#define WS_BYTES (MB_OFF + 8 * MB_STRIDE)   // 294912

static __device__ __forceinline__ void st_chunk(void* addr, f32x4 v) {
  asm volatile("global_store_dwordx4 %0, %1, off sc0 sc1"
               :: "v"(addr), "v"(v) : "memory");
}
static __device__ __forceinline__ void ld32(const void* a, f32x4& v0, f32x4& v1) {
  asm volatile("global_load_dwordx4 %0, %2, off sc0 sc1\n\t"
               "global_load_dwordx4 %1, %2, off offset:16 sc0 sc1\n\t"
               "s_waitcnt vmcnt(0)"
               : "=v"(v0), "=v"(v1) : "v"(a) : "memory");
}
static __device__ __forceinline__ void poll32(const void* a, unsigned tag,
                                              f32x4& v0, f32x4& v1) {
  ld32(a, v0, v1);
  while (__float_as_uint(v0.w) != tag || __float_as_uint(v1.w) != tag) {
    __builtin_amdgcn_s_sleep(2);
    ld32(a, v0, v1);
  }
}
// leader poll: no sleep (tight discovery cadence; only 8 CUs do this)
static __device__ __forceinline__ void poll32_ns(const void* a, unsigned tag,
                                                 f32x4& v0, f32x4& v1) {
  ld32(a, v0, v1);
  while (__float_as_uint(v0.w) != tag || __float_as_uint(v1.w) != tag) {
    ld32(a, v0, v1);
  }
}
// XCD-local mailbox ops: sc0 only (bypass L1, hit the XCD-shared L2)
static __device__ __forceinline__ void ld32_mb(const void* a, f32x4& v0, f32x4& v1) {
  asm volatile("global_load_dwordx4 %0, %2, off sc0\n\t"
               "global_load_dwordx4 %1, %2, off offset:16 sc0\n\t"
               "s_waitcnt vmcnt(0)"
               : "=v"(v0), "=v"(v1) : "v"(a) : "memory");
}
static __device__ __forceinline__ void st_mb(void* a, f32x4 v0, f32x4 v1) {
  asm volatile("global_store_dwordx4 %0, %1, off sc0\n\t"
               "global_store_dwordx4 %0, %2, off offset:16 sc0"
               :: "v"(a), "v"(v0), "v"(v1) : "memory");
}
// follower poll: mailbox first (local L2), fallback to IC ring after 64 tries;
// 4 consecutive fallbacks latch the mailbox dead (wrong-XCD-mapping rescue).
static __device__ __forceinline__ void poll_rly(const void* mb, const void* ic,
                                                unsigned tag, f32x4& v0, f32x4& v1,
                                                int& dead) {
  if (dead < 4) {
    ld32_mb(mb, v0, v1);
    int tries = 0;
    while (__float_as_uint(v0.w) != tag || __float_as_uint(v1.w) != tag) {
      if (++tries >= 64) break;
      ld32_mb(mb, v0, v1);
    }
    if (__float_as_uint(v0.w) == tag && __float_as_uint(v1.w) == tag) {
      dead = 0;
      return;
    }
    ++dead;
  }
  poll32(ic, tag, v0, v1);
}
// y-gather (ypsum chunk1 of 4 slots: lane, lane+64, lane+128, lane+192)
static __device__ __forceinline__ void ld_y4_mb(const char* a0, const char* a1,
                                                f32x4& v0, f32x4& v1, f32x4& v2, f32x4& v3) {
  asm volatile("global_load_dwordx4 %0, %4, off sc0\n\t"
               "global_load_dwordx4 %1, %4, off offset:2048 sc0\n\t"
               "global_load_dwordx4 %2, %5, off sc0\n\t"
               "global_load_dwordx4 %3, %5, off offset:2048 sc0\n\t"
               "s_waitcnt vmcnt(0)"
               : "=v"(v0), "=v"(v1), "=v"(v2), "=v"(v3)
               : "v"(a0), "v"(a1) : "memory");
}
static __device__ __forceinline__ void ld_y4_ic(const char* a0, const char* a1,
                                                f32x4& v0, f32x4& v1, f32x4& v2, f32x4& v3) {
  asm volatile("global_load_dwordx4 %0, %4, off sc0 sc1\n\t"
               "global_load_dwordx4 %1, %4, off offset:2048 sc0 sc1\n\t"
               "global_load_dwordx4 %2, %5, off sc0 sc1\n\t"
               "global_load_dwordx4 %3, %5, off offset:2048 sc0 sc1\n\t"
               "s_waitcnt vmcnt(0)"
               : "=v"(v0), "=v"(v1), "=v"(v2), "=v"(v3)
               : "v"(a0), "v"(a1) : "memory");
}
static __device__ __forceinline__ bool y4_ok(f32x4 v0, f32x4 v1, f32x4 v2, f32x4 v3,
                                             unsigned tag) {
  return __float_as_uint(v0.w) == tag && __float_as_uint(v1.w) == tag &&
         __float_as_uint(v2.w) == tag && __float_as_uint(v3.w) == tag;
}
// per-lane y partial: mailbox with IC fallback + dead-latch
static __device__ __forceinline__ float poll_y4(const char* mb_base, const char* ic_base,
                                                int lane, unsigned tag, int& dead) {
  f32x4 v0, v1, v2, v3;
  if (dead < 4) {
    const char* a0 = mb_base + lane * 32 + 16;
    const char* a1 = a0 + 4096;
    ld_y4_mb(a0, a1, v0, v1, v2, v3);
    int tries = 0;
    while (!y4_ok(v0, v1, v2, v3, tag)) {
      if (++tries >= 32) break;
      __builtin_amdgcn_s_sleep(1);
      ld_y4_mb(a0, a1, v0, v1, v2, v3);
    }
    if (y4_ok(v0, v1, v2, v3, tag)) {
      dead = 0;
      return (v0.y + v1.y) + (v2.y + v3.y);
    }
    ++dead;
  }
  const char* a0 = ic_base + lane * 32 + 16;
  const char* a1 = a0 + 4096;
  ld_y4_ic(a0, a1, v0, v1, v2, v3);
  while (!y4_ok(v0, v1, v2, v3, tag)) {
    __builtin_amdgcn_s_sleep(2);
    ld_y4_ic(a0, a1, v0, v1, v2, v3);
  }
  return (v0.y + v1.y) + (v2.y + v3.y);
}

static __device__ __forceinline__ float sigm(float v) { return 1.f / (1.f + expf(-v)); }
static __device__ __forceinline__ float tanh_f(float v) {
  float e = expf(-2.f * fabsf(v));
  return copysignf((1.f - e) / (1.f + e), v);
}
static __device__ __forceinline__ float lstm_h(float a0, float a1, float a2, float a3,
                                               float& c) {
  float ii = sigm(a0), ff = sigm(a1), gg = tanh_f(a2), oo = sigm(a3);
  c = ff * c + ii * gg;
  return oo * tanh_f(c);
}
// wave64 sum via DPP; total lands in lane 63
static __device__ __forceinline__ float dpp_red(float x) {
  x += __int_as_float(__builtin_amdgcn_update_dpp(0, __float_as_int(x), 0x111, 0xf, 0xf, true));
  x += __int_as_float(__builtin_amdgcn_update_dpp(0, __float_as_int(x), 0x112, 0xf, 0xf, true));
  x += __int_as_float(__builtin_amdgcn_update_dpp(0, __float_as_int(x), 0x114, 0xf, 0xf, true));
  x += __int_as_float(__builtin_amdgcn_update_dpp(0, __float_as_int(x), 0x118, 0xf, 0xf, true));
  x += __int_as_float(__builtin_amdgcn_update_dpp(0, __float_as_int(x), 0x142, 0xa, 0xf, true));
  x += __int_as_float(__builtin_amdgcn_update_dpp(0, __float_as_int(x), 0x143, 0xc, 0xf, true));
  return x;
}
static __device__ __forceinline__ float dot4(f32x4 a, f32x4 b) {
  return a.x * b.x + a.y * b.y + a.z * b.z + a.w * b.w;
}
// padded hidden-vector layout: chunk stride 20 floats (80B) -> conflict-free b128
static __device__ __forceinline__ int lds_idx4(int j) { return (j >> 2) * 20 + (j & 3) * 4; }

__global__ __launch_bounds__(512, 2) void lstm_fused(
    const float* __restrict__ x, const int* __restrict__ mask,
    const float* __restrict__ feat, const int* __restrict__ tfp,
    const float* __restrict__ w_ih0, const float* __restrict__ w_hh0,
    const float* __restrict__ b_ih0, const float* __restrict__ b_hh0,
    const float* __restrict__ w_ih1, const float* __restrict__ w_hh1,
    const float* __restrict__ b_ih1, const float* __restrict__ b_hh1,
    const float* __restrict__ w_ffn, const float* __restrict__ b_ffn,
    float* __restrict__ out, char* __restrict__ ws)
{
  char* h1ring = ws;
  char* h0ring = ws + H0_OFF;
  const int tid = threadIdx.x, lane = tid & 63, wv = tid >> 6;
  const int blk = blockIdx.x;
  const int u = wv & 3;
  const int m = blk * 4 + u;            // owned hidden unit (both layers)
  const bool L1w = wv < 4;              // waves 0-3: layer-1 ; waves 4-7: layer-0
  const bool leader = blk < 8;          // one relay block per XCD (round-robin map)
  char* mbx = ws + MB_OFF + (blk & 7) * MB_STRIDE;

  __shared__ __align__(16) float wh1_lds[16 * 1280];   // 80 KB
  __shared__ __align__(16) float lh0[1280];            // h0[t-1] -> h0[t]
  __shared__ __align__(16) float lh1[1280];            // h1[t-2] -> h1[t-1]
  __shared__ __align__(16) float lyp[256];             // wffn partials of staged h1
  __shared__ float g1h[4], g1yp[4], g0h[4];

  // ---- per-role weight matrix in VGPRs ----
  f32x4 W[4][4];
  {
    const float* Wsrc = L1w ? w_ih1 : w_hh0;
#pragma unroll
    for (int g = 0; g < 4; ++g) {
      const f32x4* s = reinterpret_cast<const f32x4*>(
          Wsrc + (size_t)(1024 * g + m) * 1024 + lane * 16);
#pragma unroll
      for (int q = 0; q < 4; ++q) W[g][q] = s[q];
    }
  }
  float wA[4], wB[4];
#pragma unroll
  for (int g = 0; g < 4; ++g) {
    const int r = 1024 * g + m;
    if (L1w) {
      wA[g] = (lane == 16) ? (b_ih1[r] + b_hh1[r]) : 0.f;
      wB[g] = 0.f;
    } else {
      wA[g] = (lane < 16) ? w_ih0[r * 16 + lane]
            : (lane == 16 ? (b_ih0[r] + b_hh0[r]) : 0.f);
      wB[g] = w_ih0[r * 16];
    }
  }
  const float wffn_m = w_ffn[m];
  const f32x4 wffn4 = L1w ? reinterpret_cast<const f32x4*>(w_ffn)[tid & 255]
                          : f32x4{0.f, 0.f, 0.f, 0.f};
  const float bf = b_ffn[0];
  float cc = 0.f;
  int fb0 = 0, fb1 = 0, fby = 0;        // mailbox dead-latch counters

  // ---- stage w_hh1 into LDS (pad-20 layout) ----
  for (int ch = tid; ch < 1024; ch += 512) {
    const int r = ch >> 6, kc = ch & 63;
    const int grow = 1024 * (r & 3) + blk * 4 + (r >> 2);
    const f32x4* src = reinterpret_cast<const f32x4*>(
        w_hh1 + (size_t)grow * 1024 + kc * 16);
    f32x4* dst = reinterpret_cast<f32x4*>(&wh1_lds[r * 1280 + kc * 20]);
    dst[0] = src[0]; dst[1] = src[1]; dst[2] = src[2]; dst[3] = src[3];
  }
  __syncthreads();

  const bool tf1 = (*tfp) >= 1;
  float acc0[4];

  for (int t = 0; t < SLEN; ++t) {
    const bool use_x = (t == 0) || (tf1 && mask[t] != 0);
    const bool needy = (t > 0) && !use_x;
    const unsigned tg = (unsigned)t;

    // ===== P1: L1 computes h1[t-1] ; L0 matvec (+use_x gates in P1) =====
    if (L1w) {
      if (t > 0) {
        __builtin_amdgcn_s_setprio(1);
        float a[4];
        const f32x4* h0v = reinterpret_cast<const f32x4*>(&lh0[lane * 20]);
        f32x4 p0 = h0v[0], p1 = h0v[1], p2 = h0v[2], p3 = h0v[3];
#pragma unroll
        for (int g = 0; g < 4; ++g)
          a[g] = wA[g] + dot4(W[g][0], p0) + dot4(W[g][1], p1) +
                          dot4(W[g][2], p2) + dot4(W[g][3], p3);
        if (t > 1) {
          const f32x4* h1v = reinterpret_cast<const f32x4*>(&lh1[lane * 20]);
          f32x4 q0 = h1v[0], q1 = h1v[1], q2 = h1v[2], q3 = h1v[3];
#pragma unroll
          for (int g = 0; g < 4; ++g) {
            const f32x4* wb = reinterpret_cast<const f32x4*>(
                &wh1_lds[(u * 4 + g) * 1280 + lane * 20]);
            a[g] += dot4(wb[0], q0) + dot4(wb[1], q1) +
                    dot4(wb[2], q2) + dot4(wb[3], q3);
          }
        }
#pragma unroll
        for (int g = 0; g < 4; ++g) a[g] = dpp_red(a[g]);
        if (lane == 63) {
          float h = lstm_h(a[0], a[1], a[2], a[3], cc);
          g1h[u] = h; g1yp[u] = wffn_m * h;
        }
        __builtin_amdgcn_s_setprio(0);
      }
    } else {
      float base = (lane == 0) ? (use_x ? x[t] : 0.f)
                 : (lane < 16) ? feat[t * 15 + lane - 1]
                 : (lane == 16) ? 1.f : 0.f;
#pragma unroll
      for (int g = 0; g < 4; ++g) acc0[g] = wA[g] * base;
      if (t > 0) {
        const f32x4* h0v = reinterpret_cast<const f32x4*>(&lh0[lane * 20]);
        f32x4 p0 = h0v[0], p1 = h0v[1], p2 = h0v[2], p3 = h0v[3];
#pragma unroll
        for (int g = 0; g < 4; ++g)
          acc0[g] += dot4(W[g][0], p0) + dot4(W[g][1], p1) +
                     dot4(W[g][2], p2) + dot4(W[g][3], p3);
      }
#pragma unroll
      for (int g = 0; g < 4; ++g) acc0[g] = dpp_red(acc0[g]);
      // use_x: gates need no y -> compute in P1, publish right after A
      if (use_x && lane == 63) {
        __builtin_amdgcn_s_setprio(1);
        float h = lstm_h(acc0[0], acc0[1], acc0[2], acc0[3], cc);
        g0h[u] = h;
        __builtin_amdgcn_s_setprio(0);
      }
      // deferred out[t-2] (step t-1 used x -> no direct write happened then)
      if (blk == 0 && wv == 7 && t >= 2 && (tf1 && mask[t - 1] != 0)) {
        f32x4 q = reinterpret_cast<const f32x4*>(lyp)[lane];
        float s = (q.x + q.y) + (q.z + q.w);
        s = dpp_red(s);
        if (lane == 63) out[t - 2] = s + bf;
      }
    }
    __syncthreads();  // A

    // funnel-publish h1[t-1] to IC ring (tid 0,1)
    if (t > 0 && tid < 2) {
      f32x4 v;
      if (tid == 0) { v.x = g1h[0]; v.y = g1h[1]; v.z = g1h[2]; }
      else { v.x = g1h[3]; v.y = (g1yp[0] + g1yp[1]) + (g1yp[2] + g1yp[3]); v.z = 0.f; }
      v.w = __uint_as_float((unsigned)(t - 1));
      st_chunk(h1ring + ((t - 1) & 1) * RING_PAR + blk * 32 + tid * 16, v);
    }
    // use_x: funnel-publish h0[t] EARLY (tid 2,3) - gates were done in P1
    if (use_x && tid >= 2 && tid < 4) {
      f32x4 v;
      if (tid == 2) { v.x = g0h[0]; v.y = g0h[1]; v.z = g0h[2]; }
      else { v.x = g0h[3]; v.y = 0.f; v.z = 0.f; }
      v.w = __uint_as_float(tg);
      st_chunk(h0ring + (t & 1) * RING_PAR + blk * 32 + (tid - 2) * 16, v);
    }

    // ===== P2 (needy): L1 relays/stages h1[t-1]; L0 waves self-gather y =====
    if (needy) {
      if (L1w) {
        const char* ic = h1ring + ((t - 1) & 1) * RING_PAR + tid * 32;
        char* mb = mbx + ((t - 1) & 1) * 16384 + tid * 32;
        f32x4 v0, v1;
        if (leader) { poll32_ns(ic, (unsigned)(t - 1), v0, v1); st_mb(mb, v0, v1); }
        else        { poll_rly(mb, ic, (unsigned)(t - 1), v0, v1, fb1); }
        f32x4 h4; h4.x = v0.x; h4.y = v0.y; h4.z = v0.z; h4.w = v1.x;
        *reinterpret_cast<f32x4*>(&lh1[lds_idx4(tid)]) = h4;
        lyp[tid] = dot4(wffn4, h4);
      } else {
        // barrier-free y: every L0 wave gathers the 256 canonical ypsums from
        // the XCD-local mailbox (leaders from mailbox too - written by own L1)
        float s = poll_y4(mbx + ((t - 1) & 1) * 16384,
                          h1ring + ((t - 1) & 1) * RING_PAR, lane,
                          (unsigned)(t - 1), fby);
        s = dpp_red(s);
        if (lane == 63) {
          float yy = s + bf;
          if (blk == 0 && wv == 4) out[t - 1] = yy;
#pragma unroll
          for (int g = 0; g < 4; ++g) acc0[g] += yy * wB[g];
        }
      }
      if (!L1w && lane == 63) {
        __builtin_amdgcn_s_setprio(1);
        float h = lstm_h(acc0[0], acc0[1], acc0[2], acc0[3], cc);
        g0h[u] = h;
        __builtin_amdgcn_s_setprio(0);
      }
      __syncthreads();  // D (needy only)

      // funnel-publish h0[t] to IC ring
      if (tid < 2) {
        f32x4 v;
        if (tid == 0) { v.x = g0h[0]; v.y = g0h[1]; v.z = g0h[2]; }
        else { v.x = g0h[3]; v.y = 0.f; v.z = 0.f; }
        v.w = __uint_as_float(tg);
        st_chunk(h0ring + (t & 1) * RING_PAR + blk * 32 + tid * 16, v);
      }
    }

    // ===== P3: h0 relay/staging (all) ; h1 relay/staging (use_x) =====
    if (L1w) {
      if (t > 0 && !needy) {
        const char* ic = h1ring + ((t - 1) & 1) * RING_PAR + tid * 32;
        char* mb = mbx + ((t - 1) & 1) * 16384 + tid * 32;
        f32x4 v0, v1;
        if (leader) { poll32_ns(ic, (unsigned)(t - 1), v0, v1); st_mb(mb, v0, v1); }
        else        { poll_rly(mb, ic, (unsigned)(t - 1), v0, v1, fb1); }
        f32x4 h4; h4.x = v0.x; h4.y = v0.y; h4.z = v0.z; h4.w = v1.x;
        *reinterpret_cast<f32x4*>(&lh1[lds_idx4(tid)]) = h4;
        lyp[tid] = dot4(wffn4, h4);
      }
    } else {
      const int j = tid - 256;
      const char* ic = h0ring + (t & 1) * RING_PAR + j * 32;
      char* mb = mbx + (t & 1) * 16384 + 8192 + j * 32;
      f32x4 v0, v1;
      if (leader) { poll32_ns(ic, tg, v0, v1); st_mb(mb, v0, v1); }
      else        { poll_rly(mb, ic, tg, v0, v1, fb0); }
      f32x4 h4; h4.x = v0.x; h4.y = v0.y; h4.z = v0.z; h4.w = v1.x;
      *reinterpret_cast<f32x4*>(&lh0[lds_idx4(j)]) = h4;
    }
    __syncthreads();  // E
  }

  // ===== tail: h1[SLEN-1], deferred out[SLEN-2], out[SLEN-1] =====
  if (L1w) {
    float a[4];
    const f32x4* h0v = reinterpret_cast<const f32x4*>(&lh0[lane * 20]);
    f32x4 p0 = h0v[0], p1 = h0v[1], p2 = h0v[2], p3 = h0v[3];
#pragma unroll
    for (int g = 0; g < 4; ++g)
      a[g] = wA[g] + dot4(W[g][0], p0) + dot4(W[g][1], p1) +
                      dot4(W[g][2], p2) + dot4(W[g][3], p3);
    {
      const f32x4* h1v = reinterpret_cast<const f32x4*>(&lh1[lane * 20]);
      f32x4 q0 = h1v[0], q1 = h1v[1], q2 = h1v[2], q3 = h1v[3];
#pragma unroll
      for (int g = 0; g < 4; ++g) {
        const f32x4* wb = reinterpret_cast<const f32x4*>(
            &wh1_lds[(u * 4 + g) * 1280 + lane * 20]);
        a[g] += dot4(wb[0], q0) + dot4(wb[1], q1) +
                dot4(wb[2], q2) + dot4(wb[3], q3);
      }
    }
#pragma unroll
    for (int g = 0; g < 4; ++g) a[g] = dpp_red(a[g]);
    if (lane == 63) {
      float h = lstm_h(a[0], a[1], a[2], a[3], cc);
      g1h[u] = h; g1yp[u] = wffn_m * h;
    }
  } else if (blk == 0 && wv == 7 && (tf1 && mask[SLEN - 1] != 0)) {
    // deferred out[SLEN-2] (last step used x)
    f32x4 q = reinterpret_cast<const f32x4*>(lyp)[lane];
    float s = (q.x + q.y) + (q.z + q.w);
    s = dpp_red(s);
    if (lane == 63) out[SLEN - 2] = s + bf;
  }
  __syncthreads();
  if (tid < 2) {
    f32x4 v;
    if (tid == 0) { v.x = g1h[0]; v.y = g1h[1]; v.z = g1h[2]; }
    else { v.x = g1h[3]; v.y = (g1yp[0] + g1yp[1]) + (g1yp[2] + g1yp[3]); v.z = 0.f; }
    v.w = __uint_as_float((unsigned)(SLEN - 1));
    st_chunk(h1ring + ((SLEN - 1) & 1) * RING_PAR + blk * 32 + tid * 16, v);
  }
  if (blk == 0 && wv == 0) {
    int dead = 4;  // straight to IC for the one-off tail gather
    float s = poll_y4(mbx + ((SLEN - 1) & 1) * 16384,
                      h1ring + ((SLEN - 1) & 1) * RING_PAR, lane,
                      (unsigned)(SLEN - 1), dead);
    s = dpp_red(s);
    if (lane == 63) out[SLEN - 1] = s + bf;
  }
}

extern "C" void kernel_launch(void* const* d_in, const int* in_sizes, int n_in,
                              void* d_out, int out_size, void* d_ws, size_t ws_size,
                              hipStream_t stream) {
  (void)in_sizes; (void)n_in; (void)out_size; (void)ws_size;
  const float* x      = (const float*)d_in[0];
  const int*   mask   = (const int*)  d_in[1];
  const float* feat   = (const float*)d_in[2];
  const int*   tfp    = (const int*)  d_in[3];
  const float* w_ih0  = (const float*)d_in[4];
  const float* w_hh0  = (const float*)d_in[5];
  const float* b_ih0  = (const float*)d_in[6];
  const float* b_hh0  = (const float*)d_in[7];
  const float* w_ih1  = (const float*)d_in[8];
  const float* w_hh1  = (const float*)d_in[9];
  const float* b_ih1  = (const float*)d_in[10];
  const float* b_hh1  = (const float*)d_in[11];
  const float* w_ffn  = (const float*)d_in[12];
  const float* b_ffn  = (const float*)d_in[13];
  float* out = (float*)d_out;
  char*  ws  = (char*)d_ws;

  // invalidate all ring + mailbox tags (0xFFFFFFFF never equals a step index)
  hipMemsetAsync(d_ws, 0xFF, (size_t)WS_BYTES, stream);

  lstm_fused<<<dim3(NBLK), dim3(512), 0, stream>>>(
      x, mask, feat, tfp, w_ih0, w_hh0, b_ih0, b_hh0,
      w_ih1, w_hh1, b_ih1, b_hh1, w_ffn, b_ffn, out, ws);
}

// Round 15
// 37950.366 us; speedup vs baseline: 4.3781x; 1.2543x over previous
//
#include <hip/hip_runtime.h>
#include <stdint.h>

typedef float f32x4 __attribute__((ext_vector_type(4)));

#define SLEN 8192
#define NBLK 256

// IC rings: h1 at byte 0, h0 at 16384. Each: 2 parities x 256 CUs x 2 chunks x 16B.
// CU b, chunk0 = {h[4b],h[4b+1],h[4b+2],tag}, chunk1 = {h[4b+3], ypsum_b, 0, tag}
// Ring traffic: sc0 sc1 (IC-coherent). Leaders (blk<8) relay ring -> per-XCD
// mailbox with sc0-only ops (XCD-local L2); followers poll the mailbox.
#define RING_PAR 8192
#define H0_OFF   16384
#define MB_OFF   32768
#define MB_STRIDE 32768            // per XCD: 2 par x (h1 8KB @0 + h0 8KB @8192)
#define WS_BYTES (MB_OFF + 8 * MB_STRIDE)   // 294912

static __device__ __forceinline__ void st_chunk(void* addr, f32x4 v) {
  asm volatile("global_store_dwordx4 %0, %1, off sc0 sc1"
               :: "v"(addr), "v"(v) : "memory");
}
static __device__ __forceinline__ void ld32(const void* a, f32x4& v0, f32x4& v1) {
  asm volatile("global_load_dwordx4 %0, %2, off sc0 sc1\n\t"
               "global_load_dwordx4 %1, %2, off offset:16 sc0 sc1\n\t"
               "s_waitcnt vmcnt(0)"
               : "=v"(v0), "=v"(v1) : "v"(a) : "memory");
}
static __device__ __forceinline__ void poll32(const void* a, unsigned tag,
                                              f32x4& v0, f32x4& v1) {
  ld32(a, v0, v1);
  while (__float_as_uint(v0.w) != tag || __float_as_uint(v1.w) != tag) {
    __builtin_amdgcn_s_sleep(2);
    ld32(a, v0, v1);
  }
}
// XCD-local mailbox ops: sc0 only (bypass L1, hit the XCD-shared L2)
static __device__ __forceinline__ void ld32_mb(const void* a, f32x4& v0, f32x4& v1) {
  asm volatile("global_load_dwordx4 %0, %2, off sc0\n\t"
               "global_load_dwordx4 %1, %2, off offset:16 sc0\n\t"
               "s_waitcnt vmcnt(0)"
               : "=v"(v0), "=v"(v1) : "v"(a) : "memory");
}
static __device__ __forceinline__ void st_mb(void* a, f32x4 v0, f32x4 v1) {
  asm volatile("global_store_dwordx4 %0, %1, off sc0\n\t"
               "global_store_dwordx4 %0, %2, off offset:16 sc0"
               :: "v"(a), "v"(v0), "v"(v1) : "memory");
}
// follower poll: mailbox first (local L2), fallback to IC ring after 32 tries;
// 4 consecutive fallbacks latch the mailbox dead (wrong-XCD-mapping rescue).
static __device__ __forceinline__ void poll_rly(const void* mb, const void* ic,
                                                unsigned tag, f32x4& v0, f32x4& v1,
                                                int& dead) {
  if (dead < 4) {
    ld32_mb(mb, v0, v1);
    int tries = 0;
    while (__float_as_uint(v0.w) != tag || __float_as_uint(v1.w) != tag) {
      if (++tries >= 32) break;
      __builtin_amdgcn_s_sleep(1);
      ld32_mb(mb, v0, v1);
    }
    if (__float_as_uint(v0.w) == tag && __float_as_uint(v1.w) == tag) {
      dead = 0;
      return;
    }
    ++dead;
  }
  poll32(ic, tag, v0, v1);
}
// tail y-gather from IC ring (one-off)
static __device__ __forceinline__ void ld_y4(const char* a0, const char* a1,
                                             f32x4& v0, f32x4& v1, f32x4& v2, f32x4& v3) {
  asm volatile("global_load_dwordx4 %0, %4, off sc0 sc1\n\t"
               "global_load_dwordx4 %1, %4, off offset:2048 sc0 sc1\n\t"
               "global_load_dwordx4 %2, %5, off sc0 sc1\n\t"
               "global_load_dwordx4 %3, %5, off offset:2048 sc0 sc1\n\t"
               "s_waitcnt vmcnt(0)"
               : "=v"(v0), "=v"(v1), "=v"(v2), "=v"(v3)
               : "v"(a0), "v"(a1) : "memory");
}
static __device__ __forceinline__ float poll_y4(const char* base, int lane, unsigned tag) {
  const char* a0 = base + lane * 32 + 16;
  const char* a1 = a0 + 4096;
  f32x4 v0, v1, v2, v3;
  ld_y4(a0, a1, v0, v1, v2, v3);
  while (__float_as_uint(v0.w) != tag || __float_as_uint(v1.w) != tag ||
         __float_as_uint(v2.w) != tag || __float_as_uint(v3.w) != tag) {
    __builtin_amdgcn_s_sleep(2);
    ld_y4(a0, a1, v0, v1, v2, v3);
  }
  return (v0.y + v1.y) + (v2.y + v3.y);
}

static __device__ __forceinline__ float sigm(float v) { return 1.f / (1.f + expf(-v)); }
static __device__ __forceinline__ float tanh_f(float v) {
  float e = expf(-2.f * fabsf(v));
  return copysignf((1.f - e) / (1.f + e), v);
}
static __device__ __forceinline__ float lstm_h(float a0, float a1, float a2, float a3,
                                               float& c) {
  float ii = sigm(a0), ff = sigm(a1), gg = tanh_f(a2), oo = sigm(a3);
  c = ff * c + ii * gg;
  return oo * tanh_f(c);
}
// wave64 sum via DPP; total lands in lane 63
static __device__ __forceinline__ float dpp_red(float x) {
  x += __int_as_float(__builtin_amdgcn_update_dpp(0, __float_as_int(x), 0x111, 0xf, 0xf, true));
  x += __int_as_float(__builtin_amdgcn_update_dpp(0, __float_as_int(x), 0x112, 0xf, 0xf, true));
  x += __int_as_float(__builtin_amdgcn_update_dpp(0, __float_as_int(x), 0x114, 0xf, 0xf, true));
  x += __int_as_float(__builtin_amdgcn_update_dpp(0, __float_as_int(x), 0x118, 0xf, 0xf, true));
  x += __int_as_float(__builtin_amdgcn_update_dpp(0, __float_as_int(x), 0x142, 0xa, 0xf, true));
  x += __int_as_float(__builtin_amdgcn_update_dpp(0, __float_as_int(x), 0x143, 0xc, 0xf, true));
  return x;
}
static __device__ __forceinline__ float dot4(f32x4 a, f32x4 b) {
  return a.x * b.x + a.y * b.y + a.z * b.z + a.w * b.w;
}
// padded hidden-vector layout: chunk stride 20 floats (80B) -> conflict-free b128
static __device__ __forceinline__ int lds_idx4(int j) { return (j >> 2) * 20 + (j & 3) * 4; }

__global__ __launch_bounds__(512, 2) void lstm_fused(
    const float* __restrict__ x, const int* __restrict__ mask,
    const float* __restrict__ feat, const int* __restrict__ tfp,
    const float* __restrict__ w_ih0, const float* __restrict__ w_hh0,
    const float* __restrict__ b_ih0, const float* __restrict__ b_hh0,
    const float* __restrict__ w_ih1, const float* __restrict__ w_hh1,
    const float* __restrict__ b_ih1, const float* __restrict__ b_hh1,
    const float* __restrict__ w_ffn, const float* __restrict__ b_ffn,
    float* __restrict__ out, char* __restrict__ ws)
{
  char* h1ring = ws;
  char* h0ring = ws + H0_OFF;
  const int tid = threadIdx.x, lane = tid & 63, wv = tid >> 6;
  const int blk = blockIdx.x;
  const int u = wv & 3;
  const int m = blk * 4 + u;            // owned hidden unit (both layers)
  const bool L1w = wv < 4;              // waves 0-3: layer-1 ; waves 4-7: layer-0
  const bool leader = blk < 8;          // one relay block per XCD (round-robin map)
  char* mbx = ws + MB_OFF + (blk & 7) * MB_STRIDE;

  __shared__ __align__(16) float wh1_lds[16 * 1280];   // 80 KB
  __shared__ __align__(16) float lh0[1280];            // h0[t-1] -> h0[t]
  __shared__ __align__(16) float lh1[1280];            // h1[t-2] -> h1[t-1]
  __shared__ __align__(16) float lyp[256];             // wffn partials of staged h1
  __shared__ float g1h[4], g1yp[4], g0h[4];

  // ---- per-role weight matrix in VGPRs ----
  f32x4 W[4][4];
  {
    const float* Wsrc = L1w ? w_ih1 : w_hh0;
#pragma unroll
    for (int g = 0; g < 4; ++g) {
      const f32x4* s = reinterpret_cast<const f32x4*>(
          Wsrc + (size_t)(1024 * g + m) * 1024 + lane * 16);
#pragma unroll
      for (int q = 0; q < 4; ++q) W[g][q] = s[q];
    }
  }
  float wA[4], wB[4];
#pragma unroll
  for (int g = 0; g < 4; ++g) {
    const int r = 1024 * g + m;
    if (L1w) {
      wA[g] = (lane == 16) ? (b_ih1[r] + b_hh1[r]) : 0.f;
      wB[g] = 0.f;
    } else {
      wA[g] = (lane < 16) ? w_ih0[r * 16 + lane]
            : (lane == 16 ? (b_ih0[r] + b_hh0[r]) : 0.f);
      wB[g] = w_ih0[r * 16];
    }
  }
  const float wffn_m = w_ffn[m];
  const f32x4 wffn4 = L1w ? reinterpret_cast<const f32x4*>(w_ffn)[tid & 255]
                          : f32x4{0.f, 0.f, 0.f, 0.f};
  const float bf = b_ffn[0];
  float cc = 0.f;
  int fb0 = 0, fb1 = 0;                 // mailbox dead-latch counters

  // ---- stage w_hh1 into LDS (pad-20 layout) ----
  for (int ch = tid; ch < 1024; ch += 512) {
    const int r = ch >> 6, kc = ch & 63;
    const int grow = 1024 * (r & 3) + blk * 4 + (r >> 2);
    const f32x4* src = reinterpret_cast<const f32x4*>(
        w_hh1 + (size_t)grow * 1024 + kc * 16);
    f32x4* dst = reinterpret_cast<f32x4*>(&wh1_lds[r * 1280 + kc * 20]);
    dst[0] = src[0]; dst[1] = src[1]; dst[2] = src[2]; dst[3] = src[3];
  }
  __syncthreads();

  const bool tf1 = (*tfp) >= 1;
  float acc0[4];

  for (int t = 0; t < SLEN; ++t) {
    const bool use_x = (t == 0) || (tf1 && mask[t] != 0);
    const bool needy = (t > 0) && !use_x;

    // ===== P1: L1 computes h1[t-1] ; L0 matvec (+ deferred out on wv7) =====
    if (L1w) {
      if (t > 0) {
        __builtin_amdgcn_s_setprio(1);
        float a[4];
        const f32x4* h0v = reinterpret_cast<const f32x4*>(&lh0[lane * 20]);
        f32x4 p0 = h0v[0], p1 = h0v[1], p2 = h0v[2], p3 = h0v[3];
#pragma unroll
        for (int g = 0; g < 4; ++g)
          a[g] = wA[g] + dot4(W[g][0], p0) + dot4(W[g][1], p1) +
                          dot4(W[g][2], p2) + dot4(W[g][3], p3);
        if (t > 1) {
          const f32x4* h1v = reinterpret_cast<const f32x4*>(&lh1[lane * 20]);
          f32x4 q0 = h1v[0], q1 = h1v[1], q2 = h1v[2], q3 = h1v[3];
#pragma unroll
          for (int g = 0; g < 4; ++g) {
            const f32x4* wb = reinterpret_cast<const f32x4*>(
                &wh1_lds[(u * 4 + g) * 1280 + lane * 20]);
            a[g] += dot4(wb[0], q0) + dot4(wb[1], q1) +
                    dot4(wb[2], q2) + dot4(wb[3], q3);
          }
        }
#pragma unroll
        for (int g = 0; g < 4; ++g) a[g] = dpp_red(a[g]);
        if (lane == 63) {
          float h = lstm_h(a[0], a[1], a[2], a[3], cc);
          g1h[u] = h; g1yp[u] = wffn_m * h;
        }
        __builtin_amdgcn_s_setprio(0);
      }
    } else {
      float base = (lane == 0) ? (use_x ? x[t] : 0.f)
                 : (lane < 16) ? feat[t * 15 + lane - 1]
                 : (lane == 16) ? 1.f : 0.f;
#pragma unroll
      for (int g = 0; g < 4; ++g) acc0[g] = wA[g] * base;
      if (t > 0) {
        const f32x4* h0v = reinterpret_cast<const f32x4*>(&lh0[lane * 20]);
        f32x4 p0 = h0v[0], p1 = h0v[1], p2 = h0v[2], p3 = h0v[3];
#pragma unroll
        for (int g = 0; g < 4; ++g)
          acc0[g] += dot4(W[g][0], p0) + dot4(W[g][1], p1) +
                     dot4(W[g][2], p2) + dot4(W[g][3], p3);
      }
#pragma unroll
      for (int g = 0; g < 4; ++g) acc0[g] = dpp_red(acc0[g]);
      // deferred out[t-2] (step t-1 used x -> no direct write happened then)
      if (blk == 0 && wv == 7 && t >= 2 && (tf1 && mask[t - 1] != 0)) {
        f32x4 q = reinterpret_cast<const f32x4*>(lyp)[lane];
        float s = (q.x + q.y) + (q.z + q.w);
        s = dpp_red(s);
        if (lane == 63) out[t - 2] = s + bf;
      }
    }
    __syncthreads();  // A

    // funnel-publish h1[t-1] to IC ring
    if (t > 0 && tid < 2) {
      f32x4 v;
      if (tid == 0) { v.x = g1h[0]; v.y = g1h[1]; v.z = g1h[2]; }
      else { v.x = g1h[3]; v.y = (g1yp[0] + g1yp[1]) + (g1yp[2] + g1yp[3]); v.z = 0.f; }
      v.w = __uint_as_float((unsigned)(t - 1));
      st_chunk(h1ring + ((t - 1) & 1) * RING_PAR + blk * 32 + tid * 16, v);
    }

    // ===== P2: h1 relay/staging (needy path; leader relays here when needy) =====
    if (L1w && t > 0 && needy) {
      const char* ic = h1ring + ((t - 1) & 1) * RING_PAR + tid * 32;
      char* mb = mbx + ((t - 1) & 1) * 16384 + tid * 32;
      f32x4 v0, v1;
      if (leader) { poll32(ic, (unsigned)(t - 1), v0, v1); st_mb(mb, v0, v1); }
      else        { poll_rly(mb, ic, (unsigned)(t - 1), v0, v1, fb1); }
      f32x4 h4; h4.x = v0.x; h4.y = v0.y; h4.z = v0.z; h4.w = v1.x;
      *reinterpret_cast<f32x4*>(&lh1[lds_idx4(tid)]) = h4;
      lyp[tid] = dot4(wffn4, h4);
    }
    if (needy) {
      __syncthreads();  // B: lyp complete
      // each L0 wave reduces lyp itself (fixed order, bit-identical everywhere);
      // removes barrier C + the wave0 -> lys -> lane63 LDS round-trip
      if (!L1w) {
        f32x4 q = reinterpret_cast<const f32x4*>(lyp)[lane];
        float s = (q.x + q.y) + (q.z + q.w);
        s = dpp_red(s);
        if (lane == 63) {
          float yy = s + bf;
          if (blk == 0 && wv == 4) out[t - 1] = yy;
#pragma unroll
          for (int g = 0; g < 4; ++g) acc0[g] += yy * wB[g];
        }
      }
    }
    if (!L1w && lane == 63) {
      __builtin_amdgcn_s_setprio(1);
      float h = lstm_h(acc0[0], acc0[1], acc0[2], acc0[3], cc);
      g0h[u] = h;
      __builtin_amdgcn_s_setprio(0);
    }
    __syncthreads();  // D

    // funnel-publish h0[t] to IC ring
    if (tid < 2) {
      f32x4 v;
      if (tid == 0) { v.x = g0h[0]; v.y = g0h[1]; v.z = g0h[2]; }
      else { v.x = g0h[3]; v.y = 0.f; v.z = 0.f; }
      v.w = __uint_as_float((unsigned)t);
      st_chunk(h0ring + (t & 1) * RING_PAR + blk * 32 + tid * 16, v);
    }

    // ===== P3: h0 relay/staging (all) ; h1 relay/staging (use_x) =====
    if (L1w) {
      if (t > 0 && !needy) {
        const char* ic = h1ring + ((t - 1) & 1) * RING_PAR + tid * 32;
        char* mb = mbx + ((t - 1) & 1) * 16384 + tid * 32;
        f32x4 v0, v1;
        if (leader) { poll32(ic, (unsigned)(t - 1), v0, v1); st_mb(mb, v0, v1); }
        else        { poll_rly(mb, ic, (unsigned)(t - 1), v0, v1, fb1); }
        f32x4 h4; h4.x = v0.x; h4.y = v0.y; h4.z = v0.z; h4.w = v1.x;
        *reinterpret_cast<f32x4*>(&lh1[lds_idx4(tid)]) = h4;
        lyp[tid] = dot4(wffn4, h4);
      }
    } else {
      const int j = tid - 256;
      const char* ic = h0ring + (t & 1) * RING_PAR + j * 32;
      char* mb = mbx + (t & 1) * 16384 + 8192 + j * 32;
      f32x4 v0, v1;
      if (leader) { poll32(ic, (unsigned)t, v0, v1); st_mb(mb, v0, v1); }
      else        { poll_rly(mb, ic, (unsigned)t, v0, v1, fb0); }
      f32x4 h4; h4.x = v0.x; h4.y = v0.y; h4.z = v0.z; h4.w = v1.x;
      *reinterpret_cast<f32x4*>(&lh0[lds_idx4(j)]) = h4;
    }
    __syncthreads();  // E
  }

  // ===== tail: h1[SLEN-1], deferred out[SLEN-2], out[SLEN-1] =====
  if (L1w) {
    float a[4];
    const f32x4* h0v = reinterpret_cast<const f32x4*>(&lh0[lane * 20]);
    f32x4 p0 = h0v[0], p1 = h0v[1], p2 = h0v[2], p3 = h0v[3];
#pragma unroll
    for (int g = 0; g < 4; ++g)
      a[g] = wA[g] + dot4(W[g][0], p0) + dot4(W[g][1], p1) +
                      dot4(W[g][2], p2) + dot4(W[g][3], p3);
    {
      const f32x4* h1v = reinterpret_cast<const f32x4*>(&lh1[lane * 20]);
      f32x4 q0 = h1v[0], q1 = h1v[1], q2 = h1v[2], q3 = h1v[3];
#pragma unroll
      for (int g = 0; g < 4; ++g) {
        const f32x4* wb = reinterpret_cast<const f32x4*>(
            &wh1_lds[(u * 4 + g) * 1280 + lane * 20]);
        a[g] += dot4(wb[0], q0) + dot4(wb[1], q1) +
                dot4(wb[2], q2) + dot4(wb[3], q3);
      }
    }
#pragma unroll
    for (int g = 0; g < 4; ++g) a[g] = dpp_red(a[g]);
    if (lane == 63) {
      float h = lstm_h(a[0], a[1], a[2], a[3], cc);
      g1h[u] = h; g1yp[u] = wffn_m * h;
    }
  } else if (blk == 0 && wv == 7 && (tf1 && mask[SLEN - 1] != 0)) {
    // deferred out[SLEN-2] (last step used x)
    f32x4 q = reinterpret_cast<const f32x4*>(lyp)[lane];
    float s = (q.x + q.y) + (q.z + q.w);
    s = dpp_red(s);
    if (lane == 63) out[SLEN - 2] = s + bf;
  }
  __syncthreads();
  if (tid < 2) {
    f32x4 v;
    if (tid == 0) { v.x = g1h[0]; v.y = g1h[1]; v.z = g1h[2]; }
    else { v.x = g1h[3]; v.y = (g1yp[0] + g1yp[1]) + (g1yp[2] + g1yp[3]); v.z = 0.f; }
    v.w = __uint_as_float((unsigned)(SLEN - 1));
    st_chunk(h1ring + ((SLEN - 1) & 1) * RING_PAR + blk * 32 + tid * 16, v);
  }
  if (blk == 0 && wv == 0) {
    float s = poll_y4(h1ring + ((SLEN - 1) & 1) * RING_PAR, lane, (unsigned)(SLEN - 1));
    s = dpp_red(s);
    if (lane == 63) out[SLEN - 1] = s + bf;
  }
}

extern "C" void kernel_launch(void* const* d_in, const int* in_sizes, int n_in,
                              void* d_out, int out_size, void* d_ws, size_t ws_size,
                              hipStream_t stream) {
  (void)in_sizes; (void)n_in; (void)out_size; (void)ws_size;
  const float* x      = (const float*)d_in[0];
  const int*   mask   = (const int*)  d_in[1];
  const float* feat   = (const float*)d_in[2];
  const int*   tfp    = (const int*)  d_in[3];
  const float* w_ih0  = (const float*)d_in[4];
  const float* w_hh0  = (const float*)d_in[5];
  const float* b_ih0  = (const float*)d_in[6];
  const float* b_hh0  = (const float*)d_in[7];
  const float* w_ih1  = (const float*)d_in[8];
  const float* w_hh1  = (const float*)d_in[9];
  const float* b_ih1  = (const float*)d_in[10];
  const float* b_hh1  = (const float*)d_in[11];
  const float* w_ffn  = (const float*)d_in[12];
  const float* b_ffn  = (const float*)d_in[13];
  float* out = (float*)d_out;
  char*  ws  = (char*)d_ws;

  // invalidate all ring + mailbox tags (0xFFFFFFFF never equals a step index)
  hipMemsetAsync(d_ws, 0xFF, (size_t)WS_BYTES, stream);

  lstm_fused<<<dim3(NBLK), dim3(512), 0, stream>>>(
      x, mask, feat, tfp, w_ih0, w_hh0, b_ih0, b_hh0,
      w_ih1, w_hh1, b_ih1, b_hh1, w_ffn, b_ffn, out, ws);
}